// Round 1
// baseline (1284.389 us; speedup 1.0000x reference)
//
#include <hip/hip_runtime.h>

// Problem: y[m][n] = sum_k x[m][k] * (w[n][k]*scale[n]) + bias[n]
// M=8192 (B*S), N=11008 (OUT), K=4096 (IN). fp32 in/out, bf16 MFMA compute.
#define M_DIM 8192
#define N_DIM 11008
#define K_DIM 4096
#define BM 128
#define BN 128
#define BK 32
#define NKT (K_DIM / BK)  // 128

typedef __attribute__((ext_vector_type(8))) short bf16x8;
typedef __attribute__((ext_vector_type(8))) unsigned short u16x8;
typedef __attribute__((ext_vector_type(4))) float f32x4;

__device__ __forceinline__ unsigned short f2bf(float f) {
  union { float f; unsigned u; } v; v.f = f;
  unsigned r = v.u + 0x7FFFu + ((v.u >> 16) & 1u);  // RNE to bf16
  return (unsigned short)(r >> 16);
}

__device__ __forceinline__ void gload_lds16(const unsigned short* g, unsigned short* l) {
  __builtin_amdgcn_global_load_lds(
      (const __attribute__((address_space(1))) void*)g,
      (__attribute__((address_space(3))) void*)l, 16, 0, 0);
}

// ---- pre-convert kernels (memory-bound) ----
__global__ void cvt_x_kernel(const float* __restrict__ in, unsigned short* __restrict__ o) {
  size_t i = (size_t)blockIdx.x * 256 + threadIdx.x;  // one 8-elem pack per thread
  const float4* p = (const float4*)in + i * 2;
  float4 f0 = p[0], f1 = p[1];
  u16x8 v;
  v[0] = f2bf(f0.x); v[1] = f2bf(f0.y); v[2] = f2bf(f0.z); v[3] = f2bf(f0.w);
  v[4] = f2bf(f1.x); v[5] = f2bf(f1.y); v[6] = f2bf(f1.z); v[7] = f2bf(f1.w);
  *((u16x8*)o + i) = v;
}

__global__ void cvt_w_kernel(const float* __restrict__ in, const float* __restrict__ sc,
                             unsigned short* __restrict__ o) {
  size_t i = (size_t)blockIdx.x * 256 + threadIdx.x;  // 8 elems, row = i/512 (4096/8)
  float s = sc[i >> 9];
  const float4* p = (const float4*)in + i * 2;
  float4 f0 = p[0], f1 = p[1];
  u16x8 v;
  v[0] = f2bf(f0.x * s); v[1] = f2bf(f0.y * s); v[2] = f2bf(f0.z * s); v[3] = f2bf(f0.w * s);
  v[4] = f2bf(f1.x * s); v[5] = f2bf(f1.y * s); v[6] = f2bf(f1.z * s); v[7] = f2bf(f1.w * s);
  *((u16x8*)o + i) = v;
}

// ---- GEMM: 128x128 tile, BK=32, 4 waves (2x2), 4x4 16x16x32 bf16 MFMA frags ----
template <bool PRE>
__launch_bounds__(256, 2)
__global__ void gemm_kernel(const unsigned short* __restrict__ xb,
                            const unsigned short* __restrict__ wb,
                            const float* __restrict__ xf,
                            const float* __restrict__ wf,
                            const float* __restrict__ scale,
                            const float* __restrict__ bias,
                            float* __restrict__ out) {
  __shared__ unsigned short As[2][BM * BK];  // [row][k] bf16, row stride 32
  __shared__ unsigned short Bs[2][BN * BK];  // [wrow][k] bf16

  const int tid = threadIdx.x;
  const int lane = tid & 63;
  const int wave = tid >> 6;
  const int wr = wave >> 1, wc = wave & 1;  // 2x2 wave grid, 64x64 per wave
  const int rowBase = blockIdx.y * BM;
  const int colBase = blockIdx.x * BN;

  f32x4 acc[4][4];
#pragma unroll
  for (int m = 0; m < 4; ++m)
#pragma unroll
    for (int n = 0; n < 4; ++n) acc[m][n] = (f32x4){0.f, 0.f, 0.f, 0.f};

  // hoist bias per output-col lane
  float bias_v[4];
#pragma unroll
  for (int n = 0; n < 4; ++n)
    bias_v[n] = bias[colBase + wc * 64 + n * 16 + (lane & 15)];

  // fallback staging constants (reg-staged path)
  const int frow = tid >> 1;
  const int fcol = (tid & 1) * 16;
  float fscale = 1.0f;
  if (!PRE) fscale = scale[colBase + frow];

  auto stagePre = [&](int buf, int kt) {
#pragma unroll
    for (int s = 0; s < 2; ++s) {
      int e = (s * 256 + tid) * 8;  // bf16 elem offset in tile; lds byte = t*16 (linear)
      int r = e >> 5;
      int c = e & 31;
      gload_lds16(xb + (size_t)(rowBase + r) * K_DIM + kt * BK + c, &As[buf][e]);
      gload_lds16(wb + (size_t)(colBase + r) * K_DIM + kt * BK + c, &Bs[buf][e]);
    }
  };

  float4 ra[4], rb[4];
  auto loadRegs = [&](int kt) {
    const float4* ga = (const float4*)(xf + (size_t)(rowBase + frow) * K_DIM + kt * BK + fcol);
    const float4* gb = (const float4*)(wf + (size_t)(colBase + frow) * K_DIM + kt * BK + fcol);
#pragma unroll
    for (int s = 0; s < 4; ++s) { ra[s] = ga[s]; rb[s] = gb[s]; }
  };
  auto writeLds = [&](int buf) {
    const float* fa = (const float*)ra;
    const float* fb = (const float*)rb;
#pragma unroll
    for (int h = 0; h < 2; ++h) {
      u16x8 v;
#pragma unroll
      for (int j = 0; j < 8; ++j) v[j] = f2bf(fa[h * 8 + j]);
      *(u16x8*)&As[buf][frow * BK + fcol + h * 8] = v;
    }
#pragma unroll
    for (int h = 0; h < 2; ++h) {
      u16x8 v;
#pragma unroll
      for (int j = 0; j < 8; ++j) v[j] = f2bf(fb[h * 8 + j] * fscale);
      *(u16x8*)&Bs[buf][frow * BK + fcol + h * 8] = v;
    }
  };

  auto compute = [&](int buf) {
    const int rA = lane & 15;
    const int kg = (lane >> 4) * 8;  // A[i][k]: lane=(k/8)*16+i; B[k][j]: lane=(k/8)*16+j
    bf16x8 a[4], b[4];
#pragma unroll
    for (int m = 0; m < 4; ++m)
      a[m] = *(const bf16x8*)&As[buf][(wr * 64 + m * 16 + rA) * BK + kg];
#pragma unroll
    for (int n = 0; n < 4; ++n)
      b[n] = *(const bf16x8*)&Bs[buf][(wc * 64 + n * 16 + rA) * BK + kg];
#pragma unroll
    for (int m = 0; m < 4; ++m)
#pragma unroll
      for (int n = 0; n < 4; ++n)
        acc[m][n] = __builtin_amdgcn_mfma_f32_16x16x32_bf16(a[m], b[n], acc[m][n], 0, 0, 0);
  };

  int cur = 0;
  if (PRE) {
    stagePre(0, 0);
    __syncthreads();
    for (int kt = 0; kt < NKT; ++kt) {
      if (kt + 1 < NKT) stagePre(cur ^ 1, kt + 1);
      compute(cur);
      __syncthreads();
      cur ^= 1;
    }
  } else {
    loadRegs(0);
    writeLds(0);
    __syncthreads();
    for (int kt = 0; kt < NKT; ++kt) {
      if (kt + 1 < NKT) loadRegs(kt + 1);
      compute(cur);
      if (kt + 1 < NKT) writeLds(cur ^ 1);
      __syncthreads();
      cur ^= 1;
    }
  }

  // epilogue: C/D layout col=lane&15, row=(lane>>4)*4+reg (m89/m91 verified)
  const int r0 = (lane >> 4) * 4;
  const int cc = lane & 15;
#pragma unroll
  for (int m = 0; m < 4; ++m) {
    int grow = rowBase + wr * 64 + m * 16 + r0;
#pragma unroll
    for (int n = 0; n < 4; ++n) {
      int gcol = colBase + wc * 64 + n * 16 + cc;
#pragma unroll
      for (int r = 0; r < 4; ++r)
        out[(size_t)(grow + r) * N_DIM + gcol] = acc[m][n][r] + bias_v[n];
    }
  }
}

extern "C" void kernel_launch(void* const* d_in, const int* in_sizes, int n_in,
                              void* d_out, int out_size, void* d_ws, size_t ws_size,
                              hipStream_t stream) {
  const float* x = (const float*)d_in[0];       // [8192][4096]
  const float* w = (const float*)d_in[1];       // [11008][4096]
  const float* sc = (const float*)d_in[2];      // [11008]
  const float* bi = (const float*)d_in[3];      // [11008]
  float* out = (float*)d_out;

  const size_t xe = (size_t)M_DIM * K_DIM;      // 33.55M
  const size_t we = (size_t)N_DIM * K_DIM;      // 45.09M
  const size_t need = (xe + we) * sizeof(unsigned short);  // ~157 MB

  dim3 grid(N_DIM / BN, M_DIM / BM);  // 86 x 64

  if (ws_size >= need) {
    unsigned short* xb = (unsigned short*)d_ws;
    unsigned short* wb = xb + xe;
    cvt_x_kernel<<<(unsigned)(xe / 8 / 256), 256, 0, stream>>>(x, xb);      // 16384 blocks
    cvt_w_kernel<<<(unsigned)(we / 8 / 256), 256, 0, stream>>>(w, sc, wb);  // 22016 blocks
    gemm_kernel<true><<<grid, 256, 0, stream>>>(xb, wb, nullptr, nullptr, sc, bi, out);
  } else {
    gemm_kernel<false><<<grid, 256, 0, stream>>>(nullptr, nullptr, x, w, sc, bi, out);
  }
}

// Round 2
// 1033.684 us; speedup vs baseline: 1.2425x; 1.2425x over previous
//
#include <hip/hip_runtime.h>

// y[m][n] = sum_k x[m][k] * (w[n][k]*scale[n]) + bias[n]
// M=8192, N=11008, K=4096. fp32 in/out, bf16 MFMA compute.
//
// Structure: 256x256 tile, BK=32, 8 waves (2Mx4N), 4-deep LDS ring (128 KB),
// global_load_lds staging with counted vmcnt (T4), read-side XOR swizzle (T2),
// setprio around MFMA clusters (T5), XCD-aware block swizzle (T1).
#define M_DIM 8192
#define N_DIM 11008
#define K_DIM 4096
#define BM 256
#define BN 256
#define BK 32
#define NT (K_DIM / BK)   // 128 K-steps
#define TM (M_DIM / BM)   // 32
#define TN (N_DIM / BN)   // 43
#define NWG (TM * TN)     // 1376 (divisible by 8)

typedef __attribute__((ext_vector_type(8))) short bf16x8;
typedef __attribute__((ext_vector_type(8))) unsigned short u16x8;
typedef __attribute__((ext_vector_type(4))) float f32x4;

__device__ __forceinline__ unsigned short f2bf(float f) {
  union { float f; unsigned u; } v; v.f = f;
  unsigned r = v.u + 0x7FFFu + ((v.u >> 16) & 1u);  // RNE
  return (unsigned short)(r >> 16);
}

__device__ __forceinline__ void gload_lds16(const unsigned short* g, unsigned short* l) {
  __builtin_amdgcn_global_load_lds(
      (const __attribute__((address_space(1))) void*)g,
      (__attribute__((address_space(3))) void*)l, 16, 0, 0);
}

// involution swizzle on byte offset within a 16 KB tile (256 rows x 64 B):
// XOR byte bits 4-5 with row bits 1-2 -> each 16-lane frag read spreads
// across all 32 banks (2 lanes/bank = free, m136).
__device__ __forceinline__ int swz(int b) { return b ^ ((b >> 3) & 0x30); }

// ---- pre-convert kernels (memory-bound) ----
__global__ void cvt_x_kernel(const float* __restrict__ in, unsigned short* __restrict__ o) {
  size_t i = (size_t)blockIdx.x * 256 + threadIdx.x;
  const float4* p = (const float4*)in + i * 2;
  float4 f0 = p[0], f1 = p[1];
  u16x8 v;
  v[0] = f2bf(f0.x); v[1] = f2bf(f0.y); v[2] = f2bf(f0.z); v[3] = f2bf(f0.w);
  v[4] = f2bf(f1.x); v[5] = f2bf(f1.y); v[6] = f2bf(f1.z); v[7] = f2bf(f1.w);
  *((u16x8*)o + i) = v;
}

__global__ void cvt_w_kernel(const float* __restrict__ in, const float* __restrict__ sc,
                             unsigned short* __restrict__ o) {
  size_t i = (size_t)blockIdx.x * 256 + threadIdx.x;
  float s = sc[i >> 9];  // 4096/8 = 512 packs per row
  const float4* p = (const float4*)in + i * 2;
  float4 f0 = p[0], f1 = p[1];
  u16x8 v;
  v[0] = f2bf(f0.x * s); v[1] = f2bf(f0.y * s); v[2] = f2bf(f0.z * s); v[3] = f2bf(f0.w * s);
  v[4] = f2bf(f1.x * s); v[5] = f2bf(f1.y * s); v[6] = f2bf(f1.z * s); v[7] = f2bf(f1.w * s);
  *((u16x8*)o + i) = v;
}

// ---- GEMM ----
__launch_bounds__(512, 2)
__global__ void gemm_kernel(const unsigned short* __restrict__ xb,
                            const unsigned short* __restrict__ wb,
                            const float* __restrict__ bias,
                            float* __restrict__ out) {
  // 4-ring of K-tiles: each tile = 256 rows x 32 cols bf16 = 16 KB per matrix.
  __shared__ unsigned short As[4 * 8192];  // 64 KB
  __shared__ unsigned short Bs[4 * 8192];  // 64 KB

  const int tid = threadIdx.x;
  const int lane = tid & 63;
  const int wave = tid >> 6;
  const int wr = wave >> 2;   // 0..1 -> 128-row half of A
  const int wc = wave & 3;    // 0..3 -> 64-col slice of B

  // T1: XCD-aware swizzle (bijective since NWG%8==0), column-major within
  // chunk so each XCD's concurrent blocks share one 2 MB B panel.
  int orig = blockIdx.x;
  int wg = (orig & 7) * (NWG / 8) + (orig >> 3);
  int bx = wg / TM;           // N tile 0..42
  int by = wg % TM;           // M tile 0..31
  const int rowBase = by * BM;
  const int colBase = bx * BN;

  f32x4 acc[8][4] = {};

  const int fr = lane & 15;
  const int q16 = (lane >> 4) * 16;  // byte col within 64 B row

  float bias_v[4];
#pragma unroll
  for (int n = 0; n < 4; ++n)
    bias_v[n] = bias[colBase + wc * 64 + n * 16 + fr];

  // staging: per thread 2 chunks of A + 2 of B per K-tile; linear LDS dest
  // (wave-uniform base + lane*16), pre-swizzled global source (rule #21).
  int p0 = tid * 16;
  int L0 = swz(p0), L1 = swz(p0 + 8192);
  const int sr0 = L0 >> 6, sc0 = (L0 & 63) >> 1;
  const int sr1 = (L1 >> 6), sc1 = (L1 & 63) >> 1;  // L1>>6 in [128,256)

  auto stageA = [&](int kt) {
    int b = kt & 3;
    const unsigned short* src = xb + (size_t)kt * BK;
    gload_lds16(src + (size_t)(rowBase + sr0) * K_DIM + sc0, &As[b * 8192 + (p0 >> 1)]);
    gload_lds16(src + (size_t)(rowBase + sr1) * K_DIM + sc1, &As[b * 8192 + ((p0 + 8192) >> 1)]);
  };
  auto stageB = [&](int kt) {
    int b = kt & 3;
    const unsigned short* src = wb + (size_t)kt * BK;
    gload_lds16(src + (size_t)(colBase + sr0) * K_DIM + sc0, &Bs[b * 8192 + (p0 >> 1)]);
    gload_lds16(src + (size_t)(colBase + sr1) * K_DIM + sc1, &Bs[b * 8192 + ((p0 + 8192) >> 1)]);
  };

  auto step = [&](int t, bool doStage) {
    const char* Ab = (const char*)&As[(t & 3) * 8192];
    const char* Bb = (const char*)&Bs[(t & 3) * 8192];
    if (doStage) stageA(t + 3);
    bf16x8 bfr[4], afr[4];
#pragma unroll
    for (int n = 0; n < 4; ++n) {
      int L = (wc * 64 + n * 16 + fr) * 64 + q16;
      bfr[n] = *(const bf16x8*)(Bb + swz(L));
    }
#pragma unroll
    for (int m = 0; m < 4; ++m) {
      int L = (wr * 128 + m * 16 + fr) * 64 + q16;
      afr[m] = *(const bf16x8*)(Ab + swz(L));
    }
    __builtin_amdgcn_s_setprio(1);
#pragma unroll
    for (int m = 0; m < 4; ++m)
#pragma unroll
      for (int n = 0; n < 4; ++n)
        acc[m][n] = __builtin_amdgcn_mfma_f32_16x16x32_bf16(afr[m], bfr[n], acc[m][n], 0, 0, 0);
    __builtin_amdgcn_s_setprio(0);
    if (doStage) stageB(t + 3);
#pragma unroll
    for (int m = 0; m < 4; ++m) {
      int L = (wr * 128 + (m + 4) * 16 + fr) * 64 + q16;
      afr[m] = *(const bf16x8*)(Ab + swz(L));
    }
    __builtin_amdgcn_s_setprio(1);
#pragma unroll
    for (int m = 0; m < 4; ++m)
#pragma unroll
      for (int n = 0; n < 4; ++n)
        acc[m + 4][n] = __builtin_amdgcn_mfma_f32_16x16x32_bf16(afr[m], bfr[n], acc[m + 4][n], 0, 0, 0);
    __builtin_amdgcn_s_setprio(0);
  };

  // prologue: stage tiles 0,1,2 (12 loads/thread), wait tile 0 (8 left in flight)
  stageA(0); stageB(0);
  stageA(1); stageB(1);
  stageA(2); stageB(2);
  asm volatile("s_waitcnt vmcnt(8)" ::: "memory");
  __builtin_amdgcn_s_barrier();

  // main loop: compute tile t, stage t+3; wait tile t+1 landed (t+2,t+3 stay
  // in flight -> vmcnt(8), never 0). Race-free: buf[(t+3)&3] was last read at
  // step t-1, whose ds_reads drained (lgkmcnt before its MFMAs) pre-barrier.
  for (int t = 0; t < NT - 3; ++t) {
    step(t, true);
    asm volatile("s_waitcnt vmcnt(8)" ::: "memory");
    __builtin_amdgcn_s_barrier();
  }
  // tail: drain 4 -> 0
  step(NT - 3, false);
  asm volatile("s_waitcnt vmcnt(4)" ::: "memory");
  __builtin_amdgcn_s_barrier();
  step(NT - 2, false);
  asm volatile("s_waitcnt vmcnt(0)" ::: "memory");
  __builtin_amdgcn_s_barrier();
  step(NT - 1, false);

  // epilogue: C/D layout col=lane&15, row=(lane>>4)*4+reg (m89/m91)
  const int r0 = (lane >> 4) * 4;
#pragma unroll
  for (int m = 0; m < 8; ++m) {
#pragma unroll
    for (int r = 0; r < 4; ++r) {
      size_t row = (size_t)(rowBase + wr * 128 + m * 16 + r0 + r);
      float* po = out + row * N_DIM + colBase + wc * 64 + fr;
#pragma unroll
      for (int n = 0; n < 4; ++n)
        po[n * 16] = acc[m][n][r] + bias_v[n];
    }
  }
}

extern "C" void kernel_launch(void* const* d_in, const int* in_sizes, int n_in,
                              void* d_out, int out_size, void* d_ws, size_t ws_size,
                              hipStream_t stream) {
  const float* x = (const float*)d_in[0];   // [8192][4096]
  const float* w = (const float*)d_in[1];   // [11008][4096]
  const float* sc = (const float*)d_in[2];  // [11008]
  const float* bi = (const float*)d_in[3];  // [11008]
  float* out = (float*)d_out;

  const size_t xe = (size_t)M_DIM * K_DIM;
  const size_t we = (size_t)N_DIM * K_DIM;
  unsigned short* xb = (unsigned short*)d_ws;
  unsigned short* wb = xb + xe;

  cvt_x_kernel<<<(unsigned)(xe / 8 / 256), 256, 0, stream>>>(x, xb);
  cvt_w_kernel<<<(unsigned)(we / 8 / 256), 256, 0, stream>>>(w, sc, wb);
  gemm_kernel<<<NWG, 512, 0, stream>>>(xb, wb, bi, out);
}

// Round 4
// 1009.284 us; speedup vs baseline: 1.2726x; 1.0242x over previous
//
#include <hip/hip_runtime.h>

// y[m][n] = sum_k x[m][k] * (w[n][k]*scale[n]) + bias[n]
// M=8192, N=11008, K=4096. fp32 in/out, bf16 MFMA compute.
//
// Structure: 256x256 tile, 8 waves (2Mx4N), K-step=32, 4-deep LDS panel ring
// (128 KB), global_load_lds staging with counted vmcnt(8) (T4), per-step
// 2-phase fine interleave with barriers (T3: reads+stage before barrier,
// MFMA after), read-side XOR swizzle (T2, 0 conflicts verified R2), setprio
// around MFMA clusters (T5), XCD block swizzle (T1).
#define M_DIM 8192
#define N_DIM 11008
#define K_DIM 4096
#define BM 256
#define BN 256
#define BK 32
#define NT (K_DIM / BK)   // 128 K-steps
#define TM (M_DIM / BM)   // 32
#define TN (N_DIM / BN)   // 43
#define NWG (TM * TN)     // 1376 (divisible by 8)

typedef __attribute__((ext_vector_type(8))) short bf16x8;
typedef __attribute__((ext_vector_type(8))) unsigned short u16x8;
typedef __attribute__((ext_vector_type(4))) float f32x4;

__device__ __forceinline__ unsigned short f2bf(float f) {
  union { float f; unsigned u; } v; v.f = f;
  unsigned r = v.u + 0x7FFFu + ((v.u >> 16) & 1u);  // RNE
  return (unsigned short)(r >> 16);
}

__device__ __forceinline__ void gload_lds16(const unsigned short* g, unsigned short* l) {
  __builtin_amdgcn_global_load_lds(
      (const __attribute__((address_space(1))) void*)g,
      (__attribute__((address_space(3))) void*)l, 16, 0, 0);
}

// involution swizzle on byte offset within a 16 KB panel (256 rows x 64 B):
// XOR byte bits 4-5 with row bits 1-2 -> conflict-free ds_read_b128 (R2: 0).
__device__ __forceinline__ int swz(int b) { return b ^ ((b >> 3) & 0x30); }

// ---- pre-convert kernels (memory-bound) ----
__global__ void cvt_x_kernel(const float* __restrict__ in, unsigned short* __restrict__ o) {
  size_t i = (size_t)blockIdx.x * 256 + threadIdx.x;
  const float4* p = (const float4*)in + i * 2;
  float4 f0 = p[0], f1 = p[1];
  u16x8 v;
  v[0] = f2bf(f0.x); v[1] = f2bf(f0.y); v[2] = f2bf(f0.z); v[3] = f2bf(f0.w);
  v[4] = f2bf(f1.x); v[5] = f2bf(f1.y); v[6] = f2bf(f1.z); v[7] = f2bf(f1.w);
  *((u16x8*)o + i) = v;
}

__global__ void cvt_w_kernel(const float* __restrict__ in, const float* __restrict__ sc,
                             unsigned short* __restrict__ o) {
  size_t i = (size_t)blockIdx.x * 256 + threadIdx.x;
  float s = sc[i >> 9];  // 4096/8 = 512 packs per row
  const float4* p = (const float4*)in + i * 2;
  float4 f0 = p[0], f1 = p[1];
  u16x8 v;
  v[0] = f2bf(f0.x * s); v[1] = f2bf(f0.y * s); v[2] = f2bf(f0.z * s); v[3] = f2bf(f0.w * s);
  v[4] = f2bf(f1.x * s); v[5] = f2bf(f1.y * s); v[6] = f2bf(f1.z * s); v[7] = f2bf(f1.w * s);
  *((u16x8*)o + i) = v;
}

// ---- GEMM ----
__launch_bounds__(512, 2)
__global__ void gemm_kernel(const unsigned short* __restrict__ xb,
                            const unsigned short* __restrict__ wb,
                            const float* __restrict__ bias,
                            float* __restrict__ out) {
  // 4-ring of K-step panels: each panel = 256 rows x 32 k bf16 = 16 KB.
  __shared__ unsigned short As[4 * 8192];  // 64 KB
  __shared__ unsigned short Bs[4 * 8192];  // 64 KB

  const int tid = threadIdx.x;
  const int lane = tid & 63;
  const int wave = tid >> 6;
  const int wr = wave >> 2;   // 0..1 -> 128-row half of A
  const int wc = wave & 3;    // 0..3 -> 64-col slice of B

  // T1: XCD-aware swizzle (bijective, NWG%8==0), column-major within chunk.
  int orig = blockIdx.x;
  int wg = (orig & 7) * (NWG / 8) + (orig >> 3);
  int bx = wg / TM;           // N tile 0..42
  int by = wg % TM;           // M tile 0..31
  const int rowBase = by * BM;
  const int colBase = bx * BN;

  f32x4 acc[8][4] = {};

  const int fr = lane & 15;
  const int q16 = (lane >> 4) * 16;  // byte col within 64 B row

  float bias_v[4];
#pragma unroll
  for (int n = 0; n < 4; ++n)
    bias_v[n] = bias[colBase + wc * 64 + n * 16 + fr];

  // staging: per thread 2 chunks of A + 2 of B per K-step; linear LDS dest
  // (wave-uniform base + lane*16), pre-swizzled global source (rule #21).
  int p0 = tid * 16;
  int L0 = swz(p0), L1 = swz(p0 + 8192);
  const int sr0 = L0 >> 6, sc0 = (L0 & 63) >> 1;
  const int sr1 = (L1 >> 6), sc1 = (L1 & 63) >> 1;  // L1>>6 in [128,256)

  auto stageA = [&](int kt) {
    int b = kt & 3;
    const unsigned short* src = xb + (size_t)kt * BK;
    gload_lds16(src + (size_t)(rowBase + sr0) * K_DIM + sc0, &As[b * 8192 + (p0 >> 1)]);
    gload_lds16(src + (size_t)(rowBase + sr1) * K_DIM + sc1, &As[b * 8192 + ((p0 + 8192) >> 1)]);
  };
  auto stageB = [&](int kt) {
    int b = kt & 3;
    const unsigned short* src = wb + (size_t)kt * BK;
    gload_lds16(src + (size_t)(colBase + sr0) * K_DIM + sc0, &Bs[b * 8192 + (p0 >> 1)]);
    gload_lds16(src + (size_t)(colBase + sr1) * K_DIM + sc1, &Bs[b * 8192 + ((p0 + 8192) >> 1)]);
  };

  // One K-step, split into two barrier-delimited phases (T3 fine interleave):
  //   ph1: issue all 12 ds_reads + stageA(t+3); barrier; MFMA q0 (rows 0-63)
  //   ph2: stageB(t+3); barrier; MFMA q1 (rows 64-127, bfr reused from regs)
  //   vmcnt(8); barrier   (staging ledger identical to R2 -> race-free)
  auto step = [&](int t, bool doStage) {
    const char* Ab = (const char*)&As[(t & 3) * 8192];
    const char* Bb = (const char*)&Bs[(t & 3) * 8192];
    bf16x8 bfr[4], afr0[4], afr1[4];
#pragma unroll
    for (int n = 0; n < 4; ++n) {
      int L = (wc * 64 + n * 16 + fr) * 64 + q16;
      bfr[n] = *(const bf16x8*)(Bb + swz(L));
    }
#pragma unroll
    for (int m = 0; m < 4; ++m) {
      int L = (wr * 128 + m * 16 + fr) * 64 + q16;
      afr0[m] = *(const bf16x8*)(Ab + swz(L));
    }
#pragma unroll
    for (int m = 0; m < 4; ++m) {
      int L = (wr * 128 + (m + 4) * 16 + fr) * 64 + q16;
      afr1[m] = *(const bf16x8*)(Ab + swz(L));
    }
    if (doStage) stageA(t + 3);
    __builtin_amdgcn_s_barrier();  // reads + stageA in flight during barrier
    __builtin_amdgcn_s_setprio(1);
#pragma unroll
    for (int m = 0; m < 4; ++m)
#pragma unroll
      for (int n = 0; n < 4; ++n)
        acc[m][n] = __builtin_amdgcn_mfma_f32_16x16x32_bf16(afr0[m], bfr[n], acc[m][n], 0, 0, 0);
    __builtin_amdgcn_s_setprio(0);
    if (doStage) stageB(t + 3);
    __builtin_amdgcn_s_barrier();  // mid-step: re-align waves
    __builtin_amdgcn_s_setprio(1);
#pragma unroll
    for (int m = 0; m < 4; ++m)
#pragma unroll
      for (int n = 0; n < 4; ++n)
        acc[m + 4][n] = __builtin_amdgcn_mfma_f32_16x16x32_bf16(afr1[m], bfr[n], acc[m + 4][n], 0, 0, 0);
    __builtin_amdgcn_s_setprio(0);
  };

  // prologue: stage pairs 0,1,2 (12 loads/thread), wait pair 0 (8 in flight)
  stageA(0); stageB(0);
  stageA(1); stageB(1);
  stageA(2); stageB(2);
  asm volatile("s_waitcnt vmcnt(8)" ::: "memory");
  __builtin_amdgcn_s_barrier();

  // main loop: compute tile t, stage t+3; vmcnt(8) -> pair t+1 landed, pairs
  // t+2,t+3 in flight (never drained to 0). Slot (t+3)&3 was last read at
  // step t-1, whose ds_reads completed before its consuming MFMAs -> safe.
  for (int t = 0; t < NT - 3; ++t) {
    step(t, true);
    asm volatile("s_waitcnt vmcnt(8)" ::: "memory");
    __builtin_amdgcn_s_barrier();
  }
  // tail: drain 4 -> 0
  step(NT - 3, false);
  asm volatile("s_waitcnt vmcnt(4)" ::: "memory");
  __builtin_amdgcn_s_barrier();
  step(NT - 2, false);
  asm volatile("s_waitcnt vmcnt(0)" ::: "memory");
  __builtin_amdgcn_s_barrier();
  step(NT - 1, false);

  // epilogue: C/D layout col=lane&15, row=(lane>>4)*4+reg (m89/m91)
  const int r0 = (lane >> 4) * 4;
#pragma unroll
  for (int m = 0; m < 8; ++m) {
#pragma unroll
    for (int r = 0; r < 4; ++r) {
      size_t row = (size_t)(rowBase + wr * 128 + m * 16 + r0 + r);
      float* po = out + row * N_DIM + colBase + wc * 64 + fr;
#pragma unroll
      for (int n = 0; n < 4; ++n)
        po[n * 16] = acc[m][n][r] + bias_v[n];
    }
  }
}

extern "C" void kernel_launch(void* const* d_in, const int* in_sizes, int n_in,
                              void* d_out, int out_size, void* d_ws, size_t ws_size,
                              hipStream_t stream) {
  const float* x = (const float*)d_in[0];   // [8192][4096]
  const float* w = (const float*)d_in[1];   // [11008][4096]
  const float* sc = (const float*)d_in[2];  // [11008]
  const float* bi = (const float*)d_in[3];  // [11008]
  float* out = (float*)d_out;

  const size_t xe = (size_t)M_DIM * K_DIM;
  const size_t we = (size_t)N_DIM * K_DIM;
  unsigned short* xb = (unsigned short*)d_ws;
  unsigned short* wb = xb + xe;

  cvt_x_kernel<<<(unsigned)(xe / 8 / 256), 256, 0, stream>>>(x, xb);
  cvt_w_kernel<<<(unsigned)(we / 8 / 256), 256, 0, stream>>>(w, sc, wb);
  gemm_kernel<<<NWG, 512, 0, stream>>>(xb, wb, bi, out);
}